// Round 10
// baseline (175.258 us; speedup 1.0000x reference)
//
#include <hip/hip_runtime.h>
#include <hip/hip_bf16.h>
#include <stdint.h>

#define B_ 4
#define S_ 2048
#define D_ 1024
#define H_ 16
#define HD_ 64

typedef __bf16 bf16_t;
typedef __bf16 bf16x8 __attribute__((ext_vector_type(8)));
typedef __bf16 bf16x2_t __attribute__((ext_vector_type(2)));
typedef float f32x4 __attribute__((ext_vector_type(4)));
typedef int i32x4 __attribute__((ext_vector_type(4)));

#define MFMA(a, b, c) __builtin_amdgcn_mfma_f32_16x16x32_bf16((a), (b), (c), 0, 0, 0)
#define LOG2E 1.44269504088896340736f

__device__ __forceinline__ void gload_lds16(const void* g, void* l) {
  __builtin_amdgcn_global_load_lds(
      (const __attribute__((address_space(1))) uint32_t*)g,
      (__attribute__((address_space(3))) uint32_t*)l, 16, 0, 0);
}

__device__ __forceinline__ float max3f(float a, float b, float c) {
  float d;
  asm("v_max3_f32 %0, %1, %2, %3" : "=v"(d) : "v"(a), "v"(b), "v"(c));
  return d;
}

// ---- fused weight transpose + convert: WT[n][k] = bf16(W[k][n]), 4 weights --
__global__ __launch_bounds__(256) void wt_kernel(const float* __restrict__ Wq,
                                                 const float* __restrict__ Wk,
                                                 const float* __restrict__ Wv,
                                                 const float* __restrict__ Wo,
                                                 bf16_t* __restrict__ wt0) {
  __shared__ float t[32][33];
  const int z = blockIdx.z;
  const float* w_ = z == 0 ? Wq : (z == 1 ? Wk : (z == 2 ? Wv : Wo));
  bf16_t* wt = wt0 + (size_t)z * (1u << 20);
  const int tx = threadIdx.x & 31, ty = threadIdx.x >> 5;
  const int n0 = blockIdx.x * 32, k0 = blockIdx.y * 32;
#pragma unroll
  for (int i = 0; i < 4; i++)
    t[ty + i * 8][tx] = w_[(size_t)(k0 + ty + i * 8) * D_ + n0 + tx];
  __syncthreads();
#pragma unroll
  for (int i = 0; i < 4; i++)
    wt[(size_t)(n0 + ty + i * 8) * D_ + k0 + tx] = (bf16_t)t[tx][ty + i * 8];
}

// ---- QKV GEMM, BK=32, fused f32->bf16 A conversion (T14 reg-staged A) ------
// grid.z = 0(Q)/1(K)/2(V). LDS = 2 bufs x (A[128][32] + B[128][32]) bf16
// = 32 KB -> 5 blocks/CU. B via global_load_lds; A via f32 reg-load + convert
// + ds_write. Counted vmcnt(6) = one stage (2 DMA + 4 f32x4) in flight.
// BK=32 rows are 64B = 4 chunks; fragment reads span all 4 chunks per row ->
// naturally conflict-free, NO swizzle needed.
__global__ __launch_bounds__(256) void qkv_mm(const float* __restrict__ Aq,
                                              const float* __restrict__ Ak,
                                              const float* __restrict__ Av,
                                              const bf16_t* __restrict__ wt0,
                                              const float* __restrict__ b0,
                                              const float* __restrict__ b1,
                                              const float* __restrict__ b2,
                                              bf16_t* __restrict__ out0) {
  __shared__ bf16_t smem[16384];  // 2 bufs x 8192 el (A 4096 + B 4096)

  const int z = blockIdx.z;
  const float* Af = z == 0 ? Aq : (z == 1 ? Ak : Av);
  const bf16_t* WT = wt0 + (size_t)z * 1048576u;
  const float* bias = z == 0 ? b0 : (z == 1 ? b1 : b2);
  bf16_t* out = out0 + (size_t)z * 8388608u;

  const int tid = threadIdx.x;
  const int w = tid >> 6, l = tid & 63;
  const int lr = l & 15, lg = l >> 4;
  const int wm = w >> 1, wn = w & 1;
  const int ib = (int)blockIdx.y * 8 + (int)blockIdx.x;  // 512 blocks/slice
  const int swz = (ib & 7) * 64 + (ib >> 3);
  const int m0 = (swz >> 3) * 128, n0 = (swz & 7) * 128;

  // staging: chunk = 8 elems; chunkset c in {0,1}: row = c*64 + tid>>2, kc = tid&3
  const int row0 = tid >> 2, kc4 = tid & 3;
  const float*  aS0 = Af + (size_t)(m0 + row0) * 1024 + kc4 * 8;
  const float*  aS1 = Af + (size_t)(m0 + 64 + row0) * 1024 + kc4 * 8;
  const bf16_t* bS0 = WT + (size_t)(n0 + row0) * 1024 + kc4 * 8;
  const bf16_t* bS1 = WT + (size_t)(n0 + 64 + row0) * 1024 + kc4 * 8;
  const int wsl = w * 512;                 // DMA dest slice (elements)
  const int awr = row0 * 32 + kc4 * 8;     // A ds_write addr, chunkset 0
  const int afoff = (wm * 64 + lr) * 32 + lg * 8;
  const int bfoff = 4096 + (wn * 64 + lr) * 32 + lg * 8;

  f32x4 acc[4][4];
#pragma unroll
  for (int mt = 0; mt < 4; mt++)
#pragma unroll
    for (int nt = 0; nt < 4; nt++) {
      f32x4 zz = {0.f, 0.f, 0.f, 0.f};
      acc[mt][nt] = zz;
    }

  float4 RA[4], RB[4];

#define STAGE_B(bi, kt)                                      \
  do {                                                       \
    bf16_t* bd = smem + (bi) * 8192 + 4096 + wsl;            \
    gload_lds16(bS0 + (kt), bd);                             \
    gload_lds16(bS1 + (kt), bd + 2048);                      \
  } while (0)

#define LOADA(kt, R)                                         \
  do {                                                       \
    R[0] = *(const float4*)(aS0 + (kt));                     \
    R[1] = *(const float4*)(aS0 + (kt) + 4);                 \
    R[2] = *(const float4*)(aS1 + (kt));                     \
    R[3] = *(const float4*)(aS1 + (kt) + 4);                 \
  } while (0)

#define WRITEA(bi, R)                                                        \
  do {                                                                       \
    bf16x8 v0, v1;                                                           \
    v0[0] = (bf16_t)R[0].x; v0[1] = (bf16_t)R[0].y;                          \
    v0[2] = (bf16_t)R[0].z; v0[3] = (bf16_t)R[0].w;                          \
    v0[4] = (bf16_t)R[1].x; v0[5] = (bf16_t)R[1].y;                          \
    v0[6] = (bf16_t)R[1].z; v0[7] = (bf16_t)R[1].w;                          \
    v1[0] = (bf16_t)R[2].x; v1[1] = (bf16_t)R[2].y;                          \
    v1[2] = (bf16_t)R[2].z; v1[3] = (bf16_t)R[2].w;                          \
    v1[4] = (bf16_t)R[3].x; v1[5] = (bf16_t)R[3].y;                          \
    v1[6] = (bf16_t)R[3].z; v1[7] = (bf16_t)R[3].w;                          \
    *(bf16x8*)(smem + (bi) * 8192 + awr) = v0;                               \
    *(bf16x8*)(smem + (bi) * 8192 + 2048 + awr) = v1;                       \
  } while (0)

#define COMPUTE(bi)                                                          \
  do {                                                                       \
    const bf16_t* base = smem + (bi) * 8192;                                 \
    bf16x8 af[4], bfr[4];                                                    \
    _Pragma("unroll") for (int mt = 0; mt < 4; mt++)                         \
        af[mt] = *(const bf16x8*)(base + afoff + mt * 512);                  \
    _Pragma("unroll") for (int nt = 0; nt < 4; nt++)                         \
        bfr[nt] = *(const bf16x8*)(base + bfoff + nt * 512);                 \
    _Pragma("unroll") for (int mt = 0; mt < 4; mt++)                         \
        _Pragma("unroll") for (int nt = 0; nt < 4; nt++)                     \
            acc[mt][nt] = MFMA(af[mt], bfr[nt], acc[mt][nt]);                \
  } while (0)

  // prologue: stage K-steps 0 and 1 (B->LDS, A->regs)
  STAGE_B(0, 0);
  LOADA(0, RA);
  STAGE_B(1, 32);
  LOADA(32, RB);
  asm volatile("s_waitcnt vmcnt(6)" ::: "memory");  // stage0 landed
  WRITEA(0, RA);
  asm volatile("s_waitcnt lgkmcnt(0)" ::: "memory");
  __builtin_amdgcn_s_barrier();
  __builtin_amdgcn_sched_barrier(0);

  for (int jt = 0; jt < 32; jt += 2) {
    COMPUTE(0);  // K-step jt
    __builtin_amdgcn_sched_barrier(0);
    __builtin_amdgcn_s_barrier();  // WAR buf0
    __builtin_amdgcn_sched_barrier(0);
    {
      const int kt2 = (jt + 2 < 32 ? jt + 2 : 31) * 32;  // dead re-stage at tail
      STAGE_B(0, kt2);
      LOADA(kt2, RA);
    }
    asm volatile("s_waitcnt vmcnt(6)" ::: "memory");  // stage jt+1 landed
    WRITEA(1, RB);
    asm volatile("s_waitcnt lgkmcnt(0)" ::: "memory");
    __builtin_amdgcn_s_barrier();  // RAW buf1
    __builtin_amdgcn_sched_barrier(0);
    COMPUTE(1);  // K-step jt+1
    if (jt == 30) break;
    __builtin_amdgcn_sched_barrier(0);
    __builtin_amdgcn_s_barrier();  // WAR buf1
    __builtin_amdgcn_sched_barrier(0);
    {
      const int kt3 = (jt + 3) * 32;  // jt <= 28 -> <= 992
      STAGE_B(1, kt3);
      LOADA(kt3, RB);
    }
    asm volatile("s_waitcnt vmcnt(6)" ::: "memory");  // stage jt+2 landed
    WRITEA(0, RA);
    asm volatile("s_waitcnt lgkmcnt(0)" ::: "memory");
    __builtin_amdgcn_s_barrier();  // RAW buf0
    __builtin_amdgcn_sched_barrier(0);
  }
#undef STAGE_B
#undef LOADA
#undef WRITEA
#undef COMPUTE

  float bn[4];
#pragma unroll
  for (int nt = 0; nt < 4; nt++) bn[nt] = bias[n0 + wn * 64 + nt * 16 + lr];

  if (z != 2) {
    const float sc = z == 0 ? 0.125f : 1.0f;  // 1/sqrt(HD) exact in bf16
#pragma unroll
    for (int mt = 0; mt < 4; mt++)
#pragma unroll
      for (int nt = 0; nt < 4; nt++)
#pragma unroll
        for (int r = 0; r < 4; r++) {
          int m = m0 + wm * 64 + mt * 16 + lg * 4 + r;
          int n = n0 + wn * 64 + nt * 16 + lr;
          float v = (acc[mt][nt][r] + bn[nt]) * sc;
          int b = m >> 11, s = m & 2047, h = n >> 6, hd = n & 63;
          out[(((size_t)(b * H_ + h) * S_ + s) << 6) + hd] = (bf16_t)v;
        }
  } else {  // V: transpose in LDS (stride 128, fits 32KB), write VT
    __syncthreads();  // drains vmcnt (incl. dead re-stage) + all waves done
#pragma unroll
    for (int mt = 0; mt < 4; mt++)
#pragma unroll
      for (int nt = 0; nt < 4; nt++)
#pragma unroll
        for (int r = 0; r < 4; r++) {
          int ml = wm * 64 + mt * 16 + lg * 4 + r;
          int nl = wn * 64 + nt * 16 + lr;
          smem[nl * 128 + ml] = (bf16_t)(acc[mt][nt][r] + bn[nt]);
        }
    __syncthreads();
    const int b = m0 >> 11, sbase = m0 & 2047;
#pragma unroll
    for (int c = 0; c < 8; c++) {
      int ci = c * 256 + tid;
      int dl = ci >> 4, sc2 = ci & 15;
      int n = n0 + dl, h = n >> 6, hd = n & 63;
      bf16x8 v = *reinterpret_cast<const bf16x8*>(smem + dl * 128 + sc2 * 8);
      *reinterpret_cast<bf16x8*>(out + ((size_t)((b * H_ + h) << 6) + hd) * S_ + sbase + sc2 * 8) = v;
    }
  }
}

// ---- output GEMM: C[8192x1024] = attn(bf16) @ WoT + bo, f32 out ------------
__global__ __launch_bounds__(256) void out_gemm(const bf16_t* __restrict__ A,
                                                const bf16_t* __restrict__ WT,
                                                const float* __restrict__ bias,
                                                float* __restrict__ out) {
  __shared__ bf16_t smem[32768];
  const int tid = threadIdx.x;
  const int w = tid >> 6, l = tid & 63;
  const int lr = l & 15, lg = l >> 4;
  const int wm = w >> 1, wn = w & 1;
  const int ib = (int)blockIdx.y * 8 + (int)blockIdx.x;
  const int swz = (ib & 7) * 64 + (ib >> 3);
  const int m0 = (swz >> 3) * 128, n0 = (swz & 7) * 128;

  const int row0 = tid >> 3;
  const int ks = (tid & 7) ^ (row0 & 7);
  const bf16_t* aS = A + (size_t)(m0 + row0) * 1024 + ks * 8;
  const bf16_t* bS = WT + (size_t)(n0 + row0) * 1024 + ks * 8;
  const int wsl = w * 512;

  f32x4 acc[4][4];
#pragma unroll
  for (int mt = 0; mt < 4; mt++)
#pragma unroll
    for (int nt = 0; nt < 4; nt++) {
      f32x4 zz = {0.f, 0.f, 0.f, 0.f};
      acc[mt][nt] = zz;
    }

#define STAGE(bi, kt)                                                   \
  do {                                                                  \
    bf16_t* ad = smem + (bi) * 16384 + wsl;                             \
    bf16_t* bd = smem + (bi) * 16384 + 8192 + wsl;                      \
    _Pragma("unroll") for (int c = 0; c < 4; c++) {                     \
      gload_lds16(bS + (size_t)c * 32768 + (kt), bd + c * 2048);        \
      gload_lds16(aS + (size_t)c * 32768 + (kt), ad + c * 2048);        \
    }                                                                   \
  } while (0)

  STAGE(0, 0);
  STAGE(1, 64);
  asm volatile("s_waitcnt vmcnt(8)" ::: "memory");
  __builtin_amdgcn_s_barrier();
  __builtin_amdgcn_sched_barrier(0);

  int buf = 0;
  for (int jt = 0; jt < 16; ++jt) {
    const bf16_t* alds = smem + buf * 16384;
    const bf16_t* blds = alds + 8192;
#pragma unroll
    for (int kk = 0; kk < 2; kk++) {
      bf16x8 af[4], bfr[4];
#pragma unroll
      for (int mt = 0; mt < 4; mt++) {
        int row = wm * 64 + mt * 16 + lr;
        int kc = kk * 4 + lg;
        af[mt] = *reinterpret_cast<const bf16x8*>(alds + row * 64 + ((kc ^ (row & 7)) * 8));
      }
#pragma unroll
      for (int nt = 0; nt < 4; nt++) {
        int row = wn * 64 + nt * 16 + lr;
        int kc = kk * 4 + lg;
        bfr[nt] = *reinterpret_cast<const bf16x8*>(blds + row * 64 + ((kc ^ (row & 7)) * 8));
      }
#pragma unroll
      for (int mt = 0; mt < 4; mt++)
#pragma unroll
        for (int nt = 0; nt < 4; nt++)
          acc[mt][nt] = MFMA(af[mt], bfr[nt], acc[mt][nt]);
    }
    if (jt == 15) break;
    __builtin_amdgcn_sched_barrier(0);
    __builtin_amdgcn_s_barrier();
    __builtin_amdgcn_sched_barrier(0);
    const int tn = (jt + 2 < 16) ? jt + 2 : 15;
    STAGE(buf, tn * 64);
    asm volatile("s_waitcnt vmcnt(8)" ::: "memory");
    __builtin_amdgcn_s_barrier();
    __builtin_amdgcn_sched_barrier(0);
    buf ^= 1;
  }
#undef STAGE

  float bn[4];
#pragma unroll
  for (int nt = 0; nt < 4; nt++) bn[nt] = bias[n0 + wn * 64 + nt * 16 + lr];
#pragma unroll
  for (int mt = 0; mt < 4; mt++)
#pragma unroll
    for (int nt = 0; nt < 4; nt++)
#pragma unroll
      for (int r = 0; r < 4; r++) {
        int m = m0 + wm * 64 + mt * 16 + lg * 4 + r;
        int n = n0 + wn * 64 + nt * 16 + lr;
        out[(size_t)m * D_ + n] = acc[mt][nt][r] + bn[nt];
      }
}

// ---- causal flash attention (unchanged from R9) ------------------------------
// 256 threads = 4 waves; QBLK=128 (wave w owns 32 q-rows: 2 groups of 16).
// K/V LDS fragments read ONCE per wave and shared by both groups.
// 2-buffer ring, counted vmcnt(4), raw s_barrier.
__global__ __launch_bounds__(256) void attn_k(const bf16_t* __restrict__ qh,
                                              const bf16_t* __restrict__ kh,
                                              const bf16_t* __restrict__ vt,
                                              bf16_t* __restrict__ attn) {
  __shared__ bf16_t kbuf[2][4096];
  __shared__ bf16_t vbuf[2][4096];

  const int tid = threadIdx.x, w = tid >> 6, l = tid & 63;
  const int lr = l & 15, lg = l >> 4;

  const int ib = (int)blockIdx.y * 8 + (int)blockIdx.x;  // [0,512)
  const int xcd = ib & 7, slot = ib >> 3;
  const int bh = xcd * 8 + (slot & 7);
  const int pr = slot >> 3;  // pair index 0..7
  const int b = bh >> 4, h = bh & 15;

  const int zr0 = tid >> 3, kc = tid & 7;
  const int sks = kc ^ (zr0 & 7);
  const int kprow0 = ((zr0 >> 5) & 1) * 32 + ((zr0 >> 2) & 3) * 8 + ((zr0 >> 4) & 1) * 4 + (zr0 & 3);
  const int zr1 = 32 + zr0;
  const int kprow1 = ((zr1 >> 5) & 1) * 32 + ((zr1 >> 2) & 3) * 8 + ((zr1 >> 4) & 1) * 4 + (zr1 & 3);
  const bf16_t* kbase0 = kh + ((size_t)bh * S_ + kprow0) * HD_ + sks * 8;
  const bf16_t* kbase1 = kh + ((size_t)bh * S_ + kprow1) * HD_ + sks * 8;
  const bf16_t* vbase0 = vt + ((size_t)bh * HD_ + zr0) * S_ + sks * 8;
  const bf16_t* vbase1 = vt + ((size_t)bh * HD_ + zr1) * S_ + sks * 8;

  const int xs7 = lr & 7;
  const int koffA = lr * 64 + ((lg ^ xs7) << 3);
  const int koffB = lr * 64 + (((lg ^ xs7) ^ 4) << 3);
  const int rowlim0 = w * 32 + lr;
  const int rowlim1 = w * 32 + 16 + lr;
  const int wact = w * 32 + 31;
  const int wsl = w * 512;

  bf16x8 ones;
#pragma unroll
  for (int i = 0; i < 8; i++) ones[i] = (bf16_t)1.0f;

  for (int half = 0; half < 2; half++) {
    const int qt = half ? (15 - pr) : pr;
    const int q0 = qt * 128 + w * 32;
    const int jend = 2 * qt + 1;

    const bf16_t* qp0 = qh + ((size_t)bh * S_ + q0 + lr) * HD_ + lg * 8;
    const bf16_t* qp1 = qp0 + 16 * HD_;
    bf16x8 qf00 = *(const bf16x8*)qp0;
    bf16x8 qf01 = *(const bf16x8*)(qp0 + 32);
    bf16x8 qf10 = *(const bf16x8*)qp1;
    bf16x8 qf11 = *(const bf16x8*)(qp1 + 32);

    float mi0 = -1e30f, mi1 = -1e30f;
    f32x4 o0[4], o1[4], os0, os1;
#pragma unroll
    for (int nt = 0; nt < 4; nt++) {
      f32x4 z = {0.f, 0.f, 0.f, 0.f};
      o0[nt] = z; o1[nt] = z;
    }
    {
      f32x4 z = {0.f, 0.f, 0.f, 0.f};
      os0 = z; os1 = z;
    }

    const bf16_t *ks0 = kbase0, *ks1 = kbase1, *vs0 = vbase0, *vs1 = vbase1;
    int jsrc = 0;

#define ISSUE_STAGE(kd, vd)                                     \
    do {                                                        \
      gload_lds16(ks0, (kd));                                   \
      gload_lds16(ks1, (kd) + 2048);                            \
      gload_lds16(vs0, (vd));                                   \
      gload_lds16(vs1, (vd) + 2048);                            \
      if (jsrc < jend) {                                        \
        ks0 += 64 * HD_; ks1 += 64 * HD_; vs0 += 64; vs1 += 64; \
        jsrc++;                                                 \
      }                                                         \
    } while (0)

    asm volatile("s_waitcnt vmcnt(0)" ::: "memory");

    const bf16_t *rK = kbuf[0], *rV = vbuf[0];
    const bf16_t *rKn = kbuf[1], *rVn = vbuf[1];
    bf16_t *wK = &kbuf[1][wsl], *wV = &vbuf[1][wsl];
    bf16_t *wKn = &kbuf[0][wsl], *wVn = &vbuf[0][wsl];

    ISSUE_STAGE(wKn, wVn);

    for (int jt = 0; jt <= jend; jt++) {
      ISSUE_STAGE(wK, wV);
      asm volatile("s_waitcnt vmcnt(4)" ::: "memory");
      __builtin_amdgcn_s_barrier();
      __builtin_amdgcn_sched_barrier(0);

      const int doff = jt * 64 - qt * 128;
      if (doff <= wact) {
        f32x4 s0[4], s1[4];
        __builtin_amdgcn_s_setprio(1);
#pragma unroll
        for (int nt = 0; nt < 4; nt++) {
          bf16x8 kf0 = *(const bf16x8*)(rK + koffA + nt * 1024);
          bf16x8 kf1 = *(const bf16x8*)(rK + koffB + nt * 1024);
          f32x4 a = {0.f, 0.f, 0.f, 0.f};
          a = MFMA(kf0, qf00, a);
          a = MFMA(kf1, qf01, a);
          s0[nt] = a;
          f32x4 a2 = {0.f, 0.f, 0.f, 0.f};
          a2 = MFMA(kf0, qf10, a2);
          a2 = MFMA(kf1, qf11, a2);
          s1[nt] = a2;
        }
        __builtin_amdgcn_s_setprio(0);
        if (doff >= 0) {
#pragma unroll
          for (int nt = 0; nt < 4; nt++) {
            int kvb = doff + ((nt >> 1) << 5) + ((nt & 1) << 2) + lg * 8;
#pragma unroll
            for (int r = 0; r < 4; r++) {
              if (kvb + r > rowlim0) s0[nt][r] = -1e30f;
              if (kvb + r > rowlim1) s1[nt][r] = -1e30f;
            }
          }
        }
        float ma0 = max3f(s0[0][0], s0[0][1], s0[0][2]);
        float ma1 = max3f(s0[0][3], s0[1][0], s0[1][1]);
        float ma2 = max3f(s0[1][2], s0[1][3], s0[2][0]);
        float ma3 = max3f(s0[2][1], s0[2][2], s0[2][3]);
        float ma4 = max3f(s0[3][0], s0[3][1], s0[3][2]);
        float mx0 = fmaxf(max3f(ma0, ma1, ma2), max3f(ma3, ma4, s0[3][3]));
        float mb0 = max3f(s1[0][0], s1[0][1], s1[0][2]);
        float mb1 = max3f(s1[0][3], s1[1][0], s1[1][1]);
        float mb2 = max3f(s1[1][2], s1[1][3], s1[2][0]);
        float mb3 = max3f(s1[2][1], s1[2][2], s1[2][3]);
        float mb4 = max3f(s1[3][0], s1[3][1], s1[3][2]);
        float mx1 = fmaxf(max3f(mb0, mb1, mb2), max3f(mb3, mb4, s1[3][3]));
        mx0 = fmaxf(mx0, __shfl_xor(mx0, 16));
        mx0 = fmaxf(mx0, __shfl_xor(mx0, 32));
        mx1 = fmaxf(mx1, __shfl_xor(mx1, 16));
        mx1 = fmaxf(mx1, __shfl_xor(mx1, 32));
        if (!__all((mx0 <= mi0 + 8.0f) && (mx1 <= mi1 + 8.0f))) {
          float mn0 = fmaxf(mi0, mx0), mn1 = fmaxf(mi1, mx1);
          float al0 = __builtin_amdgcn_exp2f((mi0 - mn0) * LOG2E);
          float al1 = __builtin_amdgcn_exp2f((mi1 - mn1) * LOG2E);
          mi0 = mn0; mi1 = mn1;
#pragma unroll
          for (int r = 0; r < 4; r++) {
            float a0r = __shfl(al0, lg * 4 + r);
            o0[0][r] *= a0r; o0[1][r] *= a0r; o0[2][r] *= a0r; o0[3][r] *= a0r;
            os0[r] *= a0r;
            float a1r = __shfl(al1, lg * 4 + r);
            o1[0][r] *= a1r; o1[1][r] *= a1r; o1[2][r] *= a1r; o1[3][r] *= a1r;
            os1[r] *= a1r;
          }
        }
        const float msc0 = mi0 * LOG2E, msc1 = mi1 * LOG2E;
#pragma unroll
        for (int nt = 0; nt < 4; nt++)
#pragma unroll
          for (int r = 0; r < 4; r++) {
            s0[nt][r] = __builtin_amdgcn_exp2f(s0[nt][r] * LOG2E - msc0);
            s1[nt][r] = __builtin_amdgcn_exp2f(s1[nt][r] * LOG2E - msc1);
          }
        uint32_t pk0[8], pk1[8];
#pragma unroll
        for (int nt = 0; nt < 4; nt++) {
          bf16x2_t p0lo = {(bf16_t)s0[nt][0], (bf16_t)s0[nt][1]};
          bf16x2_t p0hi = {(bf16_t)s0[nt][2], (bf16_t)s0[nt][3]};
          pk0[nt * 2] = __builtin_bit_cast(uint32_t, p0lo);
          pk0[nt * 2 + 1] = __builtin_bit_cast(uint32_t, p0hi);
          bf16x2_t p1lo = {(bf16_t)s1[nt][0], (bf16_t)s1[nt][1]};
          bf16x2_t p1hi = {(bf16_t)s1[nt][2], (bf16_t)s1[nt][3]};
          pk1[nt * 2] = __builtin_bit_cast(uint32_t, p1lo);
          pk1[nt * 2 + 1] = __builtin_bit_cast(uint32_t, p1hi);
        }
        i32x4 w00 = {(int)pk0[0], (int)pk0[1], (int)pk0[2], (int)pk0[3]};
        i32x4 w01 = {(int)pk0[4], (int)pk0[5], (int)pk0[6], (int)pk0[7]};
        i32x4 w10 = {(int)pk1[0], (int)pk1[1], (int)pk1[2], (int)pk1[3]};
        i32x4 w11 = {(int)pk1[4], (int)pk1[5], (int)pk1[6], (int)pk1[7]};
        bf16x8 pa00 = __builtin_bit_cast(bf16x8, w00);
        bf16x8 pa01 = __builtin_bit_cast(bf16x8, w01);
        bf16x8 pa10 = __builtin_bit_cast(bf16x8, w10);
        bf16x8 pa11 = __builtin_bit_cast(bf16x8, w11);
        __builtin_amdgcn_s_setprio(1);
#pragma unroll
        for (int ntd = 0; ntd < 4; ntd++) {
          bf16x8 vf0 = *(const bf16x8*)(rV + koffA + ntd * 1024);
          bf16x8 vf1 = *(const bf16x8*)(rV + koffB + ntd * 1024);
          o0[ntd] = MFMA(pa00, vf0, o0[ntd]);
          o0[ntd] = MFMA(pa01, vf1, o0[ntd]);
          o1[ntd] = MFMA(pa10, vf0, o1[ntd]);
          o1[ntd] = MFMA(pa11, vf1, o1[ntd]);
        }
        os0 = MFMA(pa00, ones, os0);
        os0 = MFMA(pa01, ones, os0);
        os1 = MFMA(pa10, ones, os1);
        os1 = MFMA(pa11, ones, os1);
        __builtin_amdgcn_s_setprio(0);
      }

      __builtin_amdgcn_sched_barrier(0);
      __builtin_amdgcn_s_barrier();
      __builtin_amdgcn_sched_barrier(0);
      { const bf16_t* t = rK; rK = rKn; rKn = t; t = rV; rV = rVn; rVn = t; }
      { bf16_t* t = wK; wK = wKn; wKn = t; t = wV; wV = wVn; wVn = t; }
    }
#undef ISSUE_STAGE
#pragma unroll
    for (int r = 0; r < 4; r++) {
      float rinv0 = 1.f / os0[r];
      float rinv1 = 1.f / os1[r];
      int srw0 = q0 + lg * 4 + r;
      int srw1 = srw0 + 16;
#pragma unroll
      for (int ntd = 0; ntd < 4; ntd++) {
        attn[((size_t)(b * S_ + srw0)) * D_ + h * 64 + ntd * 16 + lr] =
            (bf16_t)(o0[ntd][r] * rinv0);
        attn[((size_t)(b * S_ + srw1)) * D_ + h * 64 + ntd * 16 + lr] =
            (bf16_t)(o1[ntd][r] * rinv1);
      }
    }
  }
}

extern "C" void kernel_launch(void* const* d_in, const int* in_sizes, int n_in,
                              void* d_out, int out_size, void* d_ws, size_t ws_size,
                              hipStream_t stream) {
  (void)in_sizes; (void)n_in; (void)out_size; (void)ws_size;
  const float* q  = (const float*)d_in[0];
  const float* k  = (const float*)d_in[1];
  const float* v  = (const float*)d_in[2];
  // d_in[3] = mask: causal triu, hard-coded in attn_k
  const float* Wq = (const float*)d_in[4];
  const float* bq = (const float*)d_in[5];
  const float* Wk = (const float*)d_in[6];
  const float* bk = (const float*)d_in[7];
  const float* Wv = (const float*)d_in[8];
  const float* bv = (const float*)d_in[9];
  const float* Wo = (const float*)d_in[10];
  const float* bo = (const float*)d_in[11];

  char* ws = (char*)d_ws;
  bf16_t* wt0 = (bf16_t*)(ws + (0ull << 20));   // 4 x 2MB transposed weights
  bf16_t* wto = (bf16_t*)(ws + (6ull << 20));
  bf16_t* atb = (bf16_t*)(ws + (8ull << 20));   // attn output, 16MB
  bf16_t* qhb = (bf16_t*)(ws + (56ull << 20));  // Qh/Kh/VT, 3 x 16MB
  bf16_t* khb = (bf16_t*)(ws + (72ull << 20));
  bf16_t* vtb = (bf16_t*)(ws + (88ull << 20));

  dim3 tb(256);
  wt_kernel<<<dim3(32, 32, 4), tb, 0, stream>>>(Wq, Wk, Wv, Wo, wt0);
  qkv_mm<<<dim3(8, 64, 3), tb, 0, stream>>>(q, k, v, wt0, bq, bk, bv, qhb);
  attn_k<<<dim3(8, 64), tb, 0, stream>>>(qhb, khb, vtb, atb);
  out_gemm<<<dim3(8, 64), tb, 0, stream>>>(atb, wto, bo, (float*)d_out);
}

// Round 11
// 173.152 us; speedup vs baseline: 1.0122x; 1.0122x over previous
//
#include <hip/hip_runtime.h>
#include <hip/hip_bf16.h>
#include <stdint.h>

#define B_ 4
#define S_ 2048
#define D_ 1024
#define H_ 16
#define HD_ 64

typedef __bf16 bf16_t;
typedef __bf16 bf16x8 __attribute__((ext_vector_type(8)));
typedef __bf16 bf16x2_t __attribute__((ext_vector_type(2)));
typedef float f32x4 __attribute__((ext_vector_type(4)));
typedef int i32x4 __attribute__((ext_vector_type(4)));

#define MFMA(a, b, c) __builtin_amdgcn_mfma_f32_16x16x32_bf16((a), (b), (c), 0, 0, 0)
#define LOG2E 1.44269504088896340736f

__device__ __forceinline__ void gload_lds16(const void* g, void* l) {
  __builtin_amdgcn_global_load_lds(
      (const __attribute__((address_space(1))) uint32_t*)g,
      (__attribute__((address_space(3))) uint32_t*)l, 16, 0, 0);
}

__device__ __forceinline__ float max3f(float a, float b, float c) {
  float d;
  asm("v_max3_f32 %0, %1, %2, %3" : "=v"(d) : "v"(a), "v"(b), "v"(c));
  return d;
}

// ---- fused weight transpose + convert: WT[n][k] = bf16(W[k][n]), 4 weights --
__global__ __launch_bounds__(256) void wt_kernel(const float* __restrict__ Wq,
                                                 const float* __restrict__ Wk,
                                                 const float* __restrict__ Wv,
                                                 const float* __restrict__ Wo,
                                                 bf16_t* __restrict__ wt0) {
  __shared__ float t[32][33];
  const int z = blockIdx.z;
  const float* w_ = z == 0 ? Wq : (z == 1 ? Wk : (z == 2 ? Wv : Wo));
  bf16_t* wt = wt0 + (size_t)z * (1u << 20);
  const int tx = threadIdx.x & 31, ty = threadIdx.x >> 5;
  const int n0 = blockIdx.x * 32, k0 = blockIdx.y * 32;
#pragma unroll
  for (int i = 0; i < 4; i++)
    t[ty + i * 8][tx] = w_[(size_t)(k0 + ty + i * 8) * D_ + n0 + tx];
  __syncthreads();
#pragma unroll
  for (int i = 0; i < 4; i++)
    wt[(size_t)(n0 + ty + i * 8) * D_ + k0 + tx] = (bf16_t)t[tx][ty + i * 8];
}

// ---- QKV GEMM, BK=32, fused f32->bf16 A conversion (T14 reg-staged A) ------
// grid.z = 0(Q)/1(K)/2(V). LDS = 2 bufs x (A[128][32] + B[128][32]) bf16
// = 32 KB -> 5 blocks/CU. B via global_load_lds; A via f32 reg-load + convert
// + ds_write. Counted vmcnt(6) = one stage (2 DMA + 4 f32x4) in flight.
// LDS chunk swizzle: LDS[row][c] holds global k-chunk c ^ ((row>>1)&3) --
// row stride is 64B = 16 banks, so the 2-bit (row>>1) key spreads a fragment
// read's 16 lanes over 8 distinct 16B slots = 2-way (free). R10's unswizzled
// version was 8-way (8.26M conflicts). B: pre-swizzled global source, linear
// DMA dest (rule #21); A: swizzled ds_write addr (write stays tid*16-linear
// in aggregate per XOR bijectivity).
__global__ __launch_bounds__(256) void qkv_mm(const float* __restrict__ Aq,
                                              const float* __restrict__ Ak,
                                              const float* __restrict__ Av,
                                              const bf16_t* __restrict__ wt0,
                                              const float* __restrict__ b0,
                                              const float* __restrict__ b1,
                                              const float* __restrict__ b2,
                                              bf16_t* __restrict__ out0) {
  __shared__ bf16_t smem[16384];  // 2 bufs x 8192 el (A 4096 + B 4096)

  const int z = blockIdx.z;
  const float* Af = z == 0 ? Aq : (z == 1 ? Ak : Av);
  const bf16_t* WT = wt0 + (size_t)z * 1048576u;
  const float* bias = z == 0 ? b0 : (z == 1 ? b1 : b2);
  bf16_t* out = out0 + (size_t)z * 8388608u;

  const int tid = threadIdx.x;
  const int w = tid >> 6, l = tid & 63;
  const int lr = l & 15, lg = l >> 4;
  const int wm = w >> 1, wn = w & 1;
  const int ib = (int)blockIdx.y * 8 + (int)blockIdx.x;  // 512 blocks/slice
  const int swz = (ib & 7) * 64 + (ib >> 3);
  const int m0 = (swz >> 3) * 128, n0 = (swz & 7) * 128;

  // staging: chunk = 8 elems; chunkset c in {0,1}: row = c*64 + tid>>2
  const int row0 = tid >> 2, kc4 = tid & 3;
  const int sk2 = kc4 ^ ((row0 >> 1) & 3);  // swizzle key ((row0+64)>>1)&3 == (row0>>1)&3
  const float*  aS0 = Af + (size_t)(m0 + row0) * 1024 + kc4 * 8;        // A src unswizzled (reg-staged)
  const float*  aS1 = Af + (size_t)(m0 + 64 + row0) * 1024 + kc4 * 8;
  const bf16_t* bS0 = WT + (size_t)(n0 + row0) * 1024 + sk2 * 8;        // B src pre-swizzled
  const bf16_t* bS1 = WT + (size_t)(n0 + 64 + row0) * 1024 + sk2 * 8;
  const int wsl = w * 512;                   // B DMA dest slice (elements, linear)
  const int awr = row0 * 32 + sk2 * 8;       // A ds_write addr (swizzled chunk)
  const int rsw = (lg ^ ((lr >> 1) & 3)) * 8;  // read-side swizzled chunk offset
  const int afoff = (wm * 64 + lr) * 32 + rsw;
  const int bfoff = 4096 + (wn * 64 + lr) * 32 + rsw;

  f32x4 acc[4][4];
#pragma unroll
  for (int mt = 0; mt < 4; mt++)
#pragma unroll
    for (int nt = 0; nt < 4; nt++) {
      f32x4 zz = {0.f, 0.f, 0.f, 0.f};
      acc[mt][nt] = zz;
    }

  float4 RA[4], RB[4];

#define STAGE_B(bi, kt)                                      \
  do {                                                       \
    bf16_t* bd = smem + (bi) * 8192 + 4096 + wsl;            \
    gload_lds16(bS0 + (kt), bd);                             \
    gload_lds16(bS1 + (kt), bd + 2048);                      \
  } while (0)

#define LOADA(kt, R)                                         \
  do {                                                       \
    R[0] = *(const float4*)(aS0 + (kt));                     \
    R[1] = *(const float4*)(aS0 + (kt) + 4);                 \
    R[2] = *(const float4*)(aS1 + (kt));                     \
    R[3] = *(const float4*)(aS1 + (kt) + 4);                 \
  } while (0)

#define WRITEA(bi, R)                                                        \
  do {                                                                       \
    bf16x8 v0, v1;                                                           \
    v0[0] = (bf16_t)R[0].x; v0[1] = (bf16_t)R[0].y;                          \
    v0[2] = (bf16_t)R[0].z; v0[3] = (bf16_t)R[0].w;                          \
    v0[4] = (bf16_t)R[1].x; v0[5] = (bf16_t)R[1].y;                          \
    v0[6] = (bf16_t)R[1].z; v0[7] = (bf16_t)R[1].w;                          \
    v1[0] = (bf16_t)R[2].x; v1[1] = (bf16_t)R[2].y;                          \
    v1[2] = (bf16_t)R[2].z; v1[3] = (bf16_t)R[2].w;                          \
    v1[4] = (bf16_t)R[3].x; v1[5] = (bf16_t)R[3].y;                          \
    v1[6] = (bf16_t)R[3].z; v1[7] = (bf16_t)R[3].w;                          \
    *(bf16x8*)(smem + (bi) * 8192 + awr) = v0;                               \
    *(bf16x8*)(smem + (bi) * 8192 + 2048 + awr) = v1;                       \
  } while (0)

#define COMPUTE(bi)                                                          \
  do {                                                                       \
    const bf16_t* base = smem + (bi) * 8192;                                 \
    bf16x8 af[4], bfr[4];                                                    \
    _Pragma("unroll") for (int mt = 0; mt < 4; mt++)                         \
        af[mt] = *(const bf16x8*)(base + afoff + mt * 512);                  \
    _Pragma("unroll") for (int nt = 0; nt < 4; nt++)                         \
        bfr[nt] = *(const bf16x8*)(base + bfoff + nt * 512);                 \
    _Pragma("unroll") for (int mt = 0; mt < 4; mt++)                         \
        _Pragma("unroll") for (int nt = 0; nt < 4; nt++)                     \
            acc[mt][nt] = MFMA(af[mt], bfr[nt], acc[mt][nt]);                \
  } while (0)

  // prologue: stage K-steps 0 and 1 (B->LDS, A->regs)
  STAGE_B(0, 0);
  LOADA(0, RA);
  STAGE_B(1, 32);
  LOADA(32, RB);
  asm volatile("s_waitcnt vmcnt(6)" ::: "memory");  // stage0 landed
  WRITEA(0, RA);
  asm volatile("s_waitcnt lgkmcnt(0)" ::: "memory");
  __builtin_amdgcn_s_barrier();
  __builtin_amdgcn_sched_barrier(0);

  for (int jt = 0; jt < 32; jt += 2) {
    COMPUTE(0);  // K-step jt
    __builtin_amdgcn_sched_barrier(0);
    __builtin_amdgcn_s_barrier();  // WAR buf0
    __builtin_amdgcn_sched_barrier(0);
    {
      const int kt2 = (jt + 2 < 32 ? jt + 2 : 31) * 32;  // dead re-stage at tail
      STAGE_B(0, kt2);
      LOADA(kt2, RA);
    }
    asm volatile("s_waitcnt vmcnt(6)" ::: "memory");  // stage jt+1 landed
    WRITEA(1, RB);
    asm volatile("s_waitcnt lgkmcnt(0)" ::: "memory");
    __builtin_amdgcn_s_barrier();  // RAW buf1
    __builtin_amdgcn_sched_barrier(0);
    COMPUTE(1);  // K-step jt+1
    if (jt == 30) break;
    __builtin_amdgcn_sched_barrier(0);
    __builtin_amdgcn_s_barrier();  // WAR buf1
    __builtin_amdgcn_sched_barrier(0);
    {
      const int kt3 = (jt + 3) * 32;  // jt <= 28 -> <= 992
      STAGE_B(1, kt3);
      LOADA(kt3, RB);
    }
    asm volatile("s_waitcnt vmcnt(6)" ::: "memory");  // stage jt+2 landed
    WRITEA(0, RA);
    asm volatile("s_waitcnt lgkmcnt(0)" ::: "memory");
    __builtin_amdgcn_s_barrier();  // RAW buf0
    __builtin_amdgcn_sched_barrier(0);
  }
#undef STAGE_B
#undef LOADA
#undef WRITEA
#undef COMPUTE

  float bn[4];
#pragma unroll
  for (int nt = 0; nt < 4; nt++) bn[nt] = bias[n0 + wn * 64 + nt * 16 + lr];

  if (z != 2) {
    const float sc = z == 0 ? 0.125f : 1.0f;  // 1/sqrt(HD) exact in bf16
#pragma unroll
    for (int mt = 0; mt < 4; mt++)
#pragma unroll
      for (int nt = 0; nt < 4; nt++)
#pragma unroll
        for (int r = 0; r < 4; r++) {
          int m = m0 + wm * 64 + mt * 16 + lg * 4 + r;
          int n = n0 + wn * 64 + nt * 16 + lr;
          float v = (acc[mt][nt][r] + bn[nt]) * sc;
          int b = m >> 11, s = m & 2047, h = n >> 6, hd = n & 63;
          out[(((size_t)(b * H_ + h) * S_ + s) << 6) + hd] = (bf16_t)v;
        }
  } else {  // V: transpose in LDS (stride 128, fits 32KB), write VT
    __syncthreads();  // drains vmcnt (incl. dead re-stage) + all waves done
#pragma unroll
    for (int mt = 0; mt < 4; mt++)
#pragma unroll
      for (int nt = 0; nt < 4; nt++)
#pragma unroll
        for (int r = 0; r < 4; r++) {
          int ml = wm * 64 + mt * 16 + lg * 4 + r;
          int nl = wn * 64 + nt * 16 + lr;
          smem[nl * 128 + ml] = (bf16_t)(acc[mt][nt][r] + bn[nt]);
        }
    __syncthreads();
    const int b = m0 >> 11, sbase = m0 & 2047;
#pragma unroll
    for (int c = 0; c < 8; c++) {
      int ci = c * 256 + tid;
      int dl = ci >> 4, sc2 = ci & 15;
      int n = n0 + dl, h = n >> 6, hd = n & 63;
      bf16x8 v = *reinterpret_cast<const bf16x8*>(smem + dl * 128 + sc2 * 8);
      *reinterpret_cast<bf16x8*>(out + ((size_t)((b * H_ + h) << 6) + hd) * S_ + sbase + sc2 * 8) = v;
    }
  }
}

// ---- output GEMM: C[8192x1024] = attn(bf16) @ WoT + bo, f32 out ------------
__global__ __launch_bounds__(256) void out_gemm(const bf16_t* __restrict__ A,
                                                const bf16_t* __restrict__ WT,
                                                const float* __restrict__ bias,
                                                float* __restrict__ out) {
  __shared__ bf16_t smem[32768];
  const int tid = threadIdx.x;
  const int w = tid >> 6, l = tid & 63;
  const int lr = l & 15, lg = l >> 4;
  const int wm = w >> 1, wn = w & 1;
  const int ib = (int)blockIdx.y * 8 + (int)blockIdx.x;
  const int swz = (ib & 7) * 64 + (ib >> 3);
  const int m0 = (swz >> 3) * 128, n0 = (swz & 7) * 128;

  const int row0 = tid >> 3;
  const int ks = (tid & 7) ^ (row0 & 7);
  const bf16_t* aS = A + (size_t)(m0 + row0) * 1024 + ks * 8;
  const bf16_t* bS = WT + (size_t)(n0 + row0) * 1024 + ks * 8;
  const int wsl = w * 512;

  f32x4 acc[4][4];
#pragma unroll
  for (int mt = 0; mt < 4; mt++)
#pragma unroll
    for (int nt = 0; nt < 4; nt++) {
      f32x4 zz = {0.f, 0.f, 0.f, 0.f};
      acc[mt][nt] = zz;
    }

#define STAGE(bi, kt)                                                   \
  do {                                                                  \
    bf16_t* ad = smem + (bi) * 16384 + wsl;                             \
    bf16_t* bd = smem + (bi) * 16384 + 8192 + wsl;                      \
    _Pragma("unroll") for (int c = 0; c < 4; c++) {                     \
      gload_lds16(bS + (size_t)c * 32768 + (kt), bd + c * 2048);        \
      gload_lds16(aS + (size_t)c * 32768 + (kt), ad + c * 2048);        \
    }                                                                   \
  } while (0)

  STAGE(0, 0);
  STAGE(1, 64);
  asm volatile("s_waitcnt vmcnt(8)" ::: "memory");
  __builtin_amdgcn_s_barrier();
  __builtin_amdgcn_sched_barrier(0);

  int buf = 0;
  for (int jt = 0; jt < 16; ++jt) {
    const bf16_t* alds = smem + buf * 16384;
    const bf16_t* blds = alds + 8192;
#pragma unroll
    for (int kk = 0; kk < 2; kk++) {
      bf16x8 af[4], bfr[4];
#pragma unroll
      for (int mt = 0; mt < 4; mt++) {
        int row = wm * 64 + mt * 16 + lr;
        int kc = kk * 4 + lg;
        af[mt] = *reinterpret_cast<const bf16x8*>(alds + row * 64 + ((kc ^ (row & 7)) * 8));
      }
#pragma unroll
      for (int nt = 0; nt < 4; nt++) {
        int row = wn * 64 + nt * 16 + lr;
        int kc = kk * 4 + lg;
        bfr[nt] = *reinterpret_cast<const bf16x8*>(blds + row * 64 + ((kc ^ (row & 7)) * 8));
      }
#pragma unroll
      for (int mt = 0; mt < 4; mt++)
#pragma unroll
        for (int nt = 0; nt < 4; nt++)
          acc[mt][nt] = MFMA(af[mt], bfr[nt], acc[mt][nt]);
    }
    if (jt == 15) break;
    __builtin_amdgcn_sched_barrier(0);
    __builtin_amdgcn_s_barrier();
    __builtin_amdgcn_sched_barrier(0);
    const int tn = (jt + 2 < 16) ? jt + 2 : 15;
    STAGE(buf, tn * 64);
    asm volatile("s_waitcnt vmcnt(8)" ::: "memory");
    __builtin_amdgcn_s_barrier();
    __builtin_amdgcn_sched_barrier(0);
    buf ^= 1;
  }
#undef STAGE

  float bn[4];
#pragma unroll
  for (int nt = 0; nt < 4; nt++) bn[nt] = bias[n0 + wn * 64 + nt * 16 + lr];
#pragma unroll
  for (int mt = 0; mt < 4; mt++)
#pragma unroll
    for (int nt = 0; nt < 4; nt++)
#pragma unroll
      for (int r = 0; r < 4; r++) {
        int m = m0 + wm * 64 + mt * 16 + lg * 4 + r;
        int n = n0 + wn * 64 + nt * 16 + lr;
        out[(size_t)m * D_ + n] = acc[mt][nt][r] + bn[nt];
      }
}

// ---- causal flash attention (unchanged from R9) ------------------------------
// 256 threads = 4 waves; QBLK=128 (wave w owns 32 q-rows: 2 groups of 16).
// K/V LDS fragments read ONCE per wave and shared by both groups.
// 2-buffer ring, counted vmcnt(4), raw s_barrier.
__global__ __launch_bounds__(256) void attn_k(const bf16_t* __restrict__ qh,
                                              const bf16_t* __restrict__ kh,
                                              const bf16_t* __restrict__ vt,
                                              bf16_t* __restrict__ attn) {
  __shared__ bf16_t kbuf[2][4096];
  __shared__ bf16_t vbuf[2][4096];

  const int tid = threadIdx.x, w = tid >> 6, l = tid & 63;
  const int lr = l & 15, lg = l >> 4;

  const int ib = (int)blockIdx.y * 8 + (int)blockIdx.x;  // [0,512)
  const int xcd = ib & 7, slot = ib >> 3;
  const int bh = xcd * 8 + (slot & 7);
  const int pr = slot >> 3;  // pair index 0..7
  const int b = bh >> 4, h = bh & 15;

  const int zr0 = tid >> 3, kc = tid & 7;
  const int sks = kc ^ (zr0 & 7);
  const int kprow0 = ((zr0 >> 5) & 1) * 32 + ((zr0 >> 2) & 3) * 8 + ((zr0 >> 4) & 1) * 4 + (zr0 & 3);
  const int zr1 = 32 + zr0;
  const int kprow1 = ((zr1 >> 5) & 1) * 32 + ((zr1 >> 2) & 3) * 8 + ((zr1 >> 4) & 1) * 4 + (zr1 & 3);
  const bf16_t* kbase0 = kh + ((size_t)bh * S_ + kprow0) * HD_ + sks * 8;
  const bf16_t* kbase1 = kh + ((size_t)bh * S_ + kprow1) * HD_ + sks * 8;
  const bf16_t* vbase0 = vt + ((size_t)bh * HD_ + zr0) * S_ + sks * 8;
  const bf16_t* vbase1 = vt + ((size_t)bh * HD_ + zr1) * S_ + sks * 8;

  const int xs7 = lr & 7;
  const int koffA = lr * 64 + ((lg ^ xs7) << 3);
  const int koffB = lr * 64 + (((lg ^ xs7) ^ 4) << 3);
  const int rowlim0 = w * 32 + lr;
  const int rowlim1 = w * 32 + 16 + lr;
  const int wact = w * 32 + 31;
  const int wsl = w * 512;

  bf16x8 ones;
#pragma unroll
  for (int i = 0; i < 8; i++) ones[i] = (bf16_t)1.0f;

  for (int half = 0; half < 2; half++) {
    const int qt = half ? (15 - pr) : pr;
    const int q0 = qt * 128 + w * 32;
    const int jend = 2 * qt + 1;

    const bf16_t* qp0 = qh + ((size_t)bh * S_ + q0 + lr) * HD_ + lg * 8;
    const bf16_t* qp1 = qp0 + 16 * HD_;
    bf16x8 qf00 = *(const bf16x8*)qp0;
    bf16x8 qf01 = *(const bf16x8*)(qp0 + 32);
    bf16x8 qf10 = *(const bf16x8*)qp1;
    bf16x8 qf11 = *(const bf16x8*)(qp1 + 32);

    float mi0 = -1e30f, mi1 = -1e30f;
    f32x4 o0[4], o1[4], os0, os1;
#pragma unroll
    for (int nt = 0; nt < 4; nt++) {
      f32x4 z = {0.f, 0.f, 0.f, 0.f};
      o0[nt] = z; o1[nt] = z;
    }
    {
      f32x4 z = {0.f, 0.f, 0.f, 0.f};
      os0 = z; os1 = z;
    }

    const bf16_t *ks0 = kbase0, *ks1 = kbase1, *vs0 = vbase0, *vs1 = vbase1;
    int jsrc = 0;

#define ISSUE_STAGE(kd, vd)                                     \
    do {                                                        \
      gload_lds16(ks0, (kd));                                   \
      gload_lds16(ks1, (kd) + 2048);                            \
      gload_lds16(vs0, (vd));                                   \
      gload_lds16(vs1, (vd) + 2048);                            \
      if (jsrc < jend) {                                        \
        ks0 += 64 * HD_; ks1 += 64 * HD_; vs0 += 64; vs1 += 64; \
        jsrc++;                                                 \
      }                                                         \
    } while (0)

    asm volatile("s_waitcnt vmcnt(0)" ::: "memory");

    const bf16_t *rK = kbuf[0], *rV = vbuf[0];
    const bf16_t *rKn = kbuf[1], *rVn = vbuf[1];
    bf16_t *wK = &kbuf[1][wsl], *wV = &vbuf[1][wsl];
    bf16_t *wKn = &kbuf[0][wsl], *wVn = &vbuf[0][wsl];

    ISSUE_STAGE(wKn, wVn);

    for (int jt = 0; jt <= jend; jt++) {
      ISSUE_STAGE(wK, wV);
      asm volatile("s_waitcnt vmcnt(4)" ::: "memory");
      __builtin_amdgcn_s_barrier();
      __builtin_amdgcn_sched_barrier(0);

      const int doff = jt * 64 - qt * 128;
      if (doff <= wact) {
        f32x4 s0[4], s1[4];
        __builtin_amdgcn_s_setprio(1);
#pragma unroll
        for (int nt = 0; nt < 4; nt++) {
          bf16x8 kf0 = *(const bf16x8*)(rK + koffA + nt * 1024);
          bf16x8 kf1 = *(const bf16x8*)(rK + koffB + nt * 1024);
          f32x4 a = {0.f, 0.f, 0.f, 0.f};
          a = MFMA(kf0, qf00, a);
          a = MFMA(kf1, qf01, a);
          s0[nt] = a;
          f32x4 a2 = {0.f, 0.f, 0.f, 0.f};
          a2 = MFMA(kf0, qf10, a2);
          a2 = MFMA(kf1, qf11, a2);
          s1[nt] = a2;
        }
        __builtin_amdgcn_s_setprio(0);
        if (doff >= 0) {
#pragma unroll
          for (int nt = 0; nt < 4; nt++) {
            int kvb = doff + ((nt >> 1) << 5) + ((nt & 1) << 2) + lg * 8;
#pragma unroll
            for (int r = 0; r < 4; r++) {
              if (kvb + r > rowlim0) s0[nt][r] = -1e30f;
              if (kvb + r > rowlim1) s1[nt][r] = -1e30f;
            }
          }
        }
        float ma0 = max3f(s0[0][0], s0[0][1], s0[0][2]);
        float ma1 = max3f(s0[0][3], s0[1][0], s0[1][1]);
        float ma2 = max3f(s0[1][2], s0[1][3], s0[2][0]);
        float ma3 = max3f(s0[2][1], s0[2][2], s0[2][3]);
        float ma4 = max3f(s0[3][0], s0[3][1], s0[3][2]);
        float mx0 = fmaxf(max3f(ma0, ma1, ma2), max3f(ma3, ma4, s0[3][3]));
        float mb0 = max3f(s1[0][0], s1[0][1], s1[0][2]);
        float mb1 = max3f(s1[0][3], s1[1][0], s1[1][1]);
        float mb2 = max3f(s1[1][2], s1[1][3], s1[2][0]);
        float mb3 = max3f(s1[2][1], s1[2][2], s1[2][3]);
        float mb4 = max3f(s1[3][0], s1[3][1], s1[3][2]);
        float mx1 = fmaxf(max3f(mb0, mb1, mb2), max3f(mb3, mb4, s1[3][3]));
        mx0 = fmaxf(mx0, __shfl_xor(mx0, 16));
        mx0 = fmaxf(mx0, __shfl_xor(mx0, 32));
        mx1 = fmaxf(mx1, __shfl_xor(mx1, 16));
        mx1 = fmaxf(mx1, __shfl_xor(mx1, 32));
        if (!__all((mx0 <= mi0 + 8.0f) && (mx1 <= mi1 + 8.0f))) {
          float mn0 = fmaxf(mi0, mx0), mn1 = fmaxf(mi1, mx1);
          float al0 = __builtin_amdgcn_exp2f((mi0 - mn0) * LOG2E);
          float al1 = __builtin_amdgcn_exp2f((mi1 - mn1) * LOG2E);
          mi0 = mn0; mi1 = mn1;
#pragma unroll
          for (int r = 0; r < 4; r++) {
            float a0r = __shfl(al0, lg * 4 + r);
            o0[0][r] *= a0r; o0[1][r] *= a0r; o0[2][r] *= a0r; o0[3][r] *= a0r;
            os0[r] *= a0r;
            float a1r = __shfl(al1, lg * 4 + r);
            o1[0][r] *= a1r; o1[1][r] *= a1r; o1[2][r] *= a1r; o1[3][r] *= a1r;
            os1[r] *= a1r;
          }
        }
        const float msc0 = mi0 * LOG2E, msc1 = mi1 * LOG2E;
#pragma unroll
        for (int nt = 0; nt < 4; nt++)
#pragma unroll
          for (int r = 0; r < 4; r++) {
            s0[nt][r] = __builtin_amdgcn_exp2f(s0[nt][r] * LOG2E - msc0);
            s1[nt][r] = __builtin_amdgcn_exp2f(s1[nt][r] * LOG2E - msc1);
          }
        uint32_t pk0[8], pk1[8];
#pragma unroll
        for (int nt = 0; nt < 4; nt++) {
          bf16x2_t p0lo = {(bf16_t)s0[nt][0], (bf16_t)s0[nt][1]};
          bf16x2_t p0hi = {(bf16_t)s0[nt][2], (bf16_t)s0[nt][3]};
          pk0[nt * 2] = __builtin_bit_cast(uint32_t, p0lo);
          pk0[nt * 2 + 1] = __builtin_bit_cast(uint32_t, p0hi);
          bf16x2_t p1lo = {(bf16_t)s1[nt][0], (bf16_t)s1[nt][1]};
          bf16x2_t p1hi = {(bf16_t)s1[nt][2], (bf16_t)s1[nt][3]};
          pk1[nt * 2] = __builtin_bit_cast(uint32_t, p1lo);
          pk1[nt * 2 + 1] = __builtin_bit_cast(uint32_t, p1hi);
        }
        i32x4 w00 = {(int)pk0[0], (int)pk0[1], (int)pk0[2], (int)pk0[3]};
        i32x4 w01 = {(int)pk0[4], (int)pk0[5], (int)pk0[6], (int)pk0[7]};
        i32x4 w10 = {(int)pk1[0], (int)pk1[1], (int)pk1[2], (int)pk1[3]};
        i32x4 w11 = {(int)pk1[4], (int)pk1[5], (int)pk1[6], (int)pk1[7]};
        bf16x8 pa00 = __builtin_bit_cast(bf16x8, w00);
        bf16x8 pa01 = __builtin_bit_cast(bf16x8, w01);
        bf16x8 pa10 = __builtin_bit_cast(bf16x8, w10);
        bf16x8 pa11 = __builtin_bit_cast(bf16x8, w11);
        __builtin_amdgcn_s_setprio(1);
#pragma unroll
        for (int ntd = 0; ntd < 4; ntd++) {
          bf16x8 vf0 = *(const bf16x8*)(rV + koffA + ntd * 1024);
          bf16x8 vf1 = *(const bf16x8*)(rV + koffB + ntd * 1024);
          o0[ntd] = MFMA(pa00, vf0, o0[ntd]);
          o0[ntd] = MFMA(pa01, vf1, o0[ntd]);
          o1[ntd] = MFMA(pa10, vf0, o1[ntd]);
          o1[ntd] = MFMA(pa11, vf1, o1[ntd]);
        }
        os0 = MFMA(pa00, ones, os0);
        os0 = MFMA(pa01, ones, os0);
        os1 = MFMA(pa10, ones, os1);
        os1 = MFMA(pa11, ones, os1);
        __builtin_amdgcn_s_setprio(0);
      }

      __builtin_amdgcn_sched_barrier(0);
      __builtin_amdgcn_s_barrier();
      __builtin_amdgcn_sched_barrier(0);
      { const bf16_t* t = rK; rK = rKn; rKn = t; t = rV; rV = rVn; rVn = t; }
      { bf16_t* t = wK; wK = wKn; wKn = t; t = wV; wV = wVn; wVn = t; }
    }
#undef ISSUE_STAGE
#pragma unroll
    for (int r = 0; r < 4; r++) {
      float rinv0 = 1.f / os0[r];
      float rinv1 = 1.f / os1[r];
      int srw0 = q0 + lg * 4 + r;
      int srw1 = srw0 + 16;
#pragma unroll
      for (int ntd = 0; ntd < 4; ntd++) {
        attn[((size_t)(b * S_ + srw0)) * D_ + h * 64 + ntd * 16 + lr] =
            (bf16_t)(o0[ntd][r] * rinv0);
        attn[((size_t)(b * S_ + srw1)) * D_ + h * 64 + ntd * 16 + lr] =
            (bf16_t)(o1[ntd][r] * rinv1);
      }
    }
  }
}

extern "C" void kernel_launch(void* const* d_in, const int* in_sizes, int n_in,
                              void* d_out, int out_size, void* d_ws, size_t ws_size,
                              hipStream_t stream) {
  (void)in_sizes; (void)n_in; (void)out_size; (void)ws_size;
  const float* q  = (const float*)d_in[0];
  const float* k  = (const float*)d_in[1];
  const float* v  = (const float*)d_in[2];
  // d_in[3] = mask: causal triu, hard-coded in attn_k
  const float* Wq = (const float*)d_in[4];
  const float* bq = (const float*)d_in[5];
  const float* Wk = (const float*)d_in[6];
  const float* bk = (const float*)d_in[7];
  const float* Wv = (const float*)d_in[8];
  const float* bv = (const float*)d_in[9];
  const float* Wo = (const float*)d_in[10];
  const float* bo = (const float*)d_in[11];

  char* ws = (char*)d_ws;
  bf16_t* wt0 = (bf16_t*)(ws + (0ull << 20));   // 4 x 2MB transposed weights
  bf16_t* wto = (bf16_t*)(ws + (6ull << 20));
  bf16_t* atb = (bf16_t*)(ws + (8ull << 20));   // attn output, 16MB
  bf16_t* qhb = (bf16_t*)(ws + (56ull << 20));  // Qh/Kh/VT, 3 x 16MB
  bf16_t* khb = (bf16_t*)(ws + (72ull << 20));
  bf16_t* vtb = (bf16_t*)(ws + (88ull << 20));

  dim3 tb(256);
  wt_kernel<<<dim3(32, 32, 4), tb, 0, stream>>>(Wq, Wk, Wv, Wo, wt0);
  qkv_mm<<<dim3(8, 64, 3), tb, 0, stream>>>(q, k, v, wt0, bq, bk, bv, qhb);
  attn_k<<<dim3(8, 64), tb, 0, stream>>>(qhb, khb, vtb, atb);
  out_gemm<<<dim3(8, 64), tb, 0, stream>>>(atb, wto, bo, (float*)d_out);
}